// Round 4
// baseline (156.634 us; speedup 1.0000x reference)
//
#include <hip/hip_runtime.h>

// ConvT3d(32->16,k3,s2,p1)+BN+4^3 avgpool. Single persistent kernel.
// Grid = 256 blocks = (n,ht), 1 block/CU (guaranteed by VGPR/LDS budget).
// Block loops dt=0..15, sliding 3-plane LDS window (slot=id%3), wT staged
// once, all 27 B-frags in VGPRs, pool sums kept in LDS, BN via 32 global
// atomics + counter grid-barrier, output finalized in-kernel.
// Parity decomposition (validated R1-R3): even o: k=1,i=o/2;
//   odd o=2m+1: k=0 -> i=m+1 ; k=2 -> i=m.

typedef __attribute__((ext_vector_type(8))) short bf16x8;
typedef __attribute__((ext_vector_type(4))) float f32x4;

static __device__ __forceinline__ unsigned short f2bf(float f) {
    unsigned int u = __float_as_uint(f);
    u = (u + 0x7fffu + ((u >> 16) & 1u)) >> 16;   // RNE
    return (unsigned short)u;
}
static __device__ __forceinline__ unsigned pack2(float a, float b) {
    return (unsigned)f2bf(a) | ((unsigned)f2bf(b) << 16);
}

__global__ __launch_bounds__(256, 1)
void mega(const float* __restrict__ x, const float* __restrict__ w,
          const float* __restrict__ bias, const float* __restrict__ gamma,
          const float* __restrict__ beta, float* __restrict__ out,
          float* __restrict__ gsum, float* __restrict__ gsq,
          unsigned int* __restrict__ bar)
{
    const int ht = blockIdx.x & 15, n = blockIdx.x >> 4;
    const int tid = threadIdx.x;
    const int v = tid >> 6, lane = tid & 63;
    const int t = v & 1, odp = v >> 1;          // ow 16-tile, od pair
    const int c = lane & 15, qd = lane >> 4;    // co / A-row, K-granule

    __shared__ unsigned short wsm[13824];       // [tap][co][ci] 27.6 KB
    __shared__ unsigned short xs[9504];         // 3 slots x [ih3][iw33][ci32] 19 KB
    __shared__ float plds[3600];                // [co][dq][wq] pool sums 14.4 KB
    __shared__ float sred[4][16], qred[4][16], pbuf[2][8][16];
    __shared__ float bnco[32];                  // scale[16], shift[16]

    const int ih0 = ht * 2;

    // ---- stage w once: w[ci][co][tap] fp32 (coalesced) -> wsm[tap][co][ci] bf16
    #pragma unroll 1
    for (int k = 0; k < 54; ++k) {
        const int idx = tid + 256 * k;
        const int ci = idx / 432, r = idx - ci * 432;
        const int co = r / 27, tap = r - co * 27;
        wsm[tap * 512 + co * 32 + ci] = f2bf(w[idx]);
    }

    // ---- x plane staging helpers. Plane = [ih 0..2][iw 0..32][ci 0..31] bf16,
    // granule swizzle g = (ci>>3) ^ ((iw>>2)&3); iw=32 column zeroed.
    auto stage_single = [&](int id) {
        const int slot = id % 3;
        #pragma unroll
        for (int r = 0; r < 2; ++r) {
            const int combo = r * 16 + (tid >> 4);
            if (combo >= 24) continue;
            const int seg = combo & 7, ihl = combo >> 3;
            const int ih = ih0 + ihl;
            const int cp = tid & 15, ci0 = cp * 2;
            f32x4 a = {0.f,0.f,0.f,0.f}, b = {0.f,0.f,0.f,0.f};
            if (id < 32 && ih < 32) {
                const float* px = x + (((n*32 + ci0)*32 + id)*32 + ih)*32 + seg*4;
                a = *(const f32x4*)px;
                b = *(const f32x4*)(px + 32768);
            }
            const int base = slot * 3168 + ihl * 1056;
            #pragma unroll
            for (int j = 0; j < 4; ++j) {
                const int iw = seg * 4 + j;
                const int g = (cp >> 2) ^ ((iw >> 2) & 3);
                *(unsigned*)(xs + base + iw*32 + g*8 + 2*(cp & 3)) = pack2(a[j], b[j]);
            }
            if (seg == 7)
                *(unsigned*)(xs + base + 1024 + (cp >> 2)*8 + 2*(cp & 3)) = 0u;
        }
    };

    f32x4 F[6];   // prefetch buffer: 2 planes, 3 tasks x 2 ci-rows
    auto prefetch = [&](int idA) {
        #pragma unroll
        for (int r = 0; r < 3; ++r) {
            const int combo = r * 16 + (tid >> 4);
            const int seg = combo & 7, q = combo >> 3;
            const int p = (q >= 3) ? 1 : 0, ihl = q - 3 * p;
            const int id = idA + p, ih = ih0 + ihl;
            const int ci0 = (tid & 15) * 2;
            f32x4 z = {0.f,0.f,0.f,0.f};
            F[2*r] = z; F[2*r+1] = z;
            if (id < 32 && ih < 32) {
                const float* px = x + (((n*32 + ci0)*32 + id)*32 + ih)*32 + seg*4;
                F[2*r]   = *(const f32x4*)px;
                F[2*r+1] = *(const f32x4*)(px + 32768);
            }
        }
    };
    auto writebatch = [&](int idA) {
        #pragma unroll
        for (int r = 0; r < 3; ++r) {
            const int combo = r * 16 + (tid >> 4);
            const int seg = combo & 7, q = combo >> 3;
            const int p = (q >= 3) ? 1 : 0, ihl = q - 3 * p;
            const int id = idA + p;
            const int slot = id % 3;
            const int cp = tid & 15;
            const int base = slot * 3168 + ihl * 1056;
            #pragma unroll
            for (int j = 0; j < 4; ++j) {
                const int iw = seg * 4 + j;
                const int g = (cp >> 2) ^ ((iw >> 2) & 3);
                *(unsigned*)(xs + base + iw*32 + g*8 + 2*(cp & 3)) =
                    pack2(F[2*r][j], F[2*r+1][j]);
            }
            if (seg == 7)
                *(unsigned*)(xs + base + 1024 + (cp >> 2)*8 + 2*(cp & 3)) = 0u;
        }
    };

    stage_single(0); stage_single(1); stage_single(2);
    prefetch(3);                       // batch {3,4} in flight

    __syncthreads();                   // wsm + planes 0..2 ready

    // ---- all 27 B fragments resident in VGPRs
    bf16x8 Bfr[27];
    #pragma unroll
    for (int tap = 0; tap < 27; ++tap)
        Bfr[tap] = *(const bf16x8*)(wsm + tap * 512 + c * 32 + qd * 8);

    // h-tap tables (validated R2/R3): hi -> (kh, ohl) pairs
    constexpr int HN[3] = {2, 3, 1};
    constexpr int HKH[3][3] = {{1,2,0},{0,1,2},{0,0,0}};
    constexpr int HOH[3][3] = {{0,1,0},{1,2,3},{3,0,0}};

    const float bv = bias[c];
    float s = 0.f, sq = 0.f;

    for (int dt = 0; dt < 16; ++dt) {
        const int b0 = ((2*dt + odp)     % 3) * 3168;
        const int b1 = ((2*dt + odp + 1) % 3) * 3168;
        auto LDA = [&](int base, int hi, int sofs) -> bf16x8 {
            const int iw = 16*t + sofs + c;
            const int g  = qd ^ ((iw >> 2) & 3);
            return *(const bf16x8*)(xs + base + hi*1056 + iw*32 + g*8);
        };
        bf16x8 A0[3], A1[3], C0[3], C1[3];
        #pragma unroll
        for (int hi = 0; hi < 3; ++hi) {
            A0[hi] = LDA(b0, hi, 0); A1[hi] = LDA(b0, hi, 1);
            C0[hi] = LDA(b1, hi, 0); C1[hi] = LDA(b1, hi, 1);
        }
        f32x4 acc[2][4][2];
        #pragma unroll
        for (int ol = 0; ol < 2; ++ol)
            #pragma unroll
            for (int oh = 0; oh < 4; ++oh)
                #pragma unroll
                for (int par = 0; par < 2; ++par)
                    acc[ol][oh][par] = (f32x4){0.f,0.f,0.f,0.f};

        #pragma unroll
        for (int hi = 0; hi < 3; ++hi)
            #pragma unroll
            for (int j = 0; j < 3; ++j)
                if (j < HN[hi]) {
                    const int kh = HKH[hi][j], oh = HOH[hi][j];
                    // di=odp: kd=1 -> ol0, kd=2 -> ol1
                    acc[0][oh][0] = __builtin_amdgcn_mfma_f32_16x16x32_bf16(
                        A0[hi], Bfr[9 + kh*3 + 1], acc[0][oh][0], 0, 0, 0);
                    acc[0][oh][1] = __builtin_amdgcn_mfma_f32_16x16x32_bf16(
                        A1[hi], Bfr[9 + kh*3 + 0], acc[0][oh][1], 0, 0, 0);
                    acc[0][oh][1] = __builtin_amdgcn_mfma_f32_16x16x32_bf16(
                        A0[hi], Bfr[9 + kh*3 + 2], acc[0][oh][1], 0, 0, 0);
                    acc[1][oh][0] = __builtin_amdgcn_mfma_f32_16x16x32_bf16(
                        A0[hi], Bfr[18 + kh*3 + 1], acc[1][oh][0], 0, 0, 0);
                    acc[1][oh][1] = __builtin_amdgcn_mfma_f32_16x16x32_bf16(
                        A1[hi], Bfr[18 + kh*3 + 0], acc[1][oh][1], 0, 0, 0);
                    acc[1][oh][1] = __builtin_amdgcn_mfma_f32_16x16x32_bf16(
                        A0[hi], Bfr[18 + kh*3 + 2], acc[1][oh][1], 0, 0, 0);
                    // di=odp+1: kd=0 -> ol1
                    acc[1][oh][0] = __builtin_amdgcn_mfma_f32_16x16x32_bf16(
                        C0[hi], Bfr[kh*3 + 1], acc[1][oh][0], 0, 0, 0);
                    acc[1][oh][1] = __builtin_amdgcn_mfma_f32_16x16x32_bf16(
                        C1[hi], Bfr[kh*3 + 0], acc[1][oh][1], 0, 0, 0);
                    acc[1][oh][1] = __builtin_amdgcn_mfma_f32_16x16x32_bf16(
                        C0[hi], Bfr[kh*3 + 2], acc[1][oh][1], 0, 0, 0);
                }

        // ---- per-iter epilogue: bias, BN stats (masked), pool partials
        float P[2] = {0.f, 0.f};
        #pragma unroll
        for (int ol = 0; ol < 2; ++ol) {
            const bool odok = !(dt == 15 && odp == 1 && ol == 1);
            #pragma unroll
            for (int oh = 0; oh < 4; ++oh) {
                const bool ohok = !(ht == 15 && oh == 3);
                #pragma unroll
                for (int par = 0; par < 2; ++par)
                    #pragma unroll
                    for (int r = 0; r < 4; ++r) {
                        const float val = acc[ol][oh][par][r] + bv;
                        const bool owok = !(par == 1 && t == 1 && qd == 3 && r == 3);
                        const float mk = (odok && ohok && owok) ? 1.f : 0.f;
                        s += mk * val; sq += mk * val * val;
                        P[r >> 1] += val;
                    }
            }
        }
        if (odp == 0 && dt < 15 && ht < 15) {
            pbuf[t][2*qd + 0][c] = P[0];
            pbuf[t][2*qd + 1][c] = P[1];
        }
        __syncthreads();               // compute & pbuf done; slots reusable
        if (odp == 1 && dt < 15 && ht < 15) {
            #pragma unroll
            for (int jj = 0; jj < 2; ++jj) {
                const int jl = 2*qd + jj, jg = 8*t + jl;
                if (jg < 15)
                    plds[c*225 + dt*15 + jg] = pbuf[t][jl][c] + P[jj];
            }
        }
        if (dt < 15) {
            writebatch(2*dt + 3);      // planes {2dt+3, 2dt+4}
            if (dt < 14) prefetch(2*dt + 5);
        }
        __syncthreads();               // new planes visible for next iter
    }

    // ---- block-level BN stat reduction -> global atomics
    s  += __shfl_xor(s, 16, 64);  s  += __shfl_xor(s, 32, 64);
    sq += __shfl_xor(sq, 16, 64); sq += __shfl_xor(sq, 32, 64);
    if (lane < 16) { sred[v][lane] = s; qred[v][lane] = sq; }
    __syncthreads();
    if (tid < 16) {
        atomicAdd(&gsum[tid], sred[0][tid]+sred[1][tid]+sred[2][tid]+sred[3][tid]);
        atomicAdd(&gsq [tid], qred[0][tid]+qred[1][tid]+qred[2][tid]+qred[3][tid]);
    }

    // ---- grid barrier (256 co-resident blocks)
    __syncthreads();
    if (tid == 0) {
        __threadfence();
        atomicAdd(bar, 1u);
        while (atomicAdd(bar, 0u) < 256u) __builtin_amdgcn_s_sleep(2);
        __threadfence();
    }
    __syncthreads();

    // ---- BN finalize (per co)
    if (tid < 16) {
        const float S = atomicAdd(&gsum[tid], 0.f);
        const float Q = atomicAdd(&gsq[tid], 0.f);
        const float cnt  = 16.f * 63.f * 63.f * 63.f;
        const float mean = S / cnt;
        const float var  = Q / cnt - mean * mean;
        const float inv  = rsqrtf(var + 1e-5f);
        const float sc   = inv * gamma[tid];
        bnco[tid]      = sc;
        bnco[16 + tid] = beta[tid] - mean * sc;
    }
    __syncthreads();

    // ---- finalize this block's pooled slice -> out
    if (ht < 15) {
        for (int i = tid; i < 3600; i += 256) {
            const int co = i / 225, rem = i - co * 225;
            const int dq = rem / 15, wq = rem - dq * 15;
            out[((n*16 + co)*15 + dq)*225 + ht*15 + wq] =
                plds[i] * (1.f/64.f) * bnco[co] + bnco[16 + co];
        }
    }
}

extern "C" void kernel_launch(void* const* d_in, const int* in_sizes, int n_in,
                              void* d_out, int out_size, void* d_ws, size_t ws_size,
                              hipStream_t stream)
{
    const float* x     = (const float*)d_in[0];
    const float* w     = (const float*)d_in[1];
    const float* b     = (const float*)d_in[2];
    const float* gamma = (const float*)d_in[3];
    const float* beta  = (const float*)d_in[4];
    float* out = (float*)d_out;

    float* gsum = (float*)d_ws;                 // 16 floats
    float* gsq  = gsum + 16;                    // 16 floats
    unsigned int* bar = (unsigned int*)(gsq + 16);

    hipMemsetAsync(d_ws, 0, 256, stream);       // zero gsum/gsq/bar
    mega<<<256, 256, 0, stream>>>(x, w, b, gamma, beta, out, gsum, gsq, bar);
}

// Round 5
// 144.225 us; speedup vs baseline: 1.0860x; 1.0860x over previous
//
#include <hip/hip_runtime.h>

// ConvT3d(32->16,k3,s2,p1)+BN+4^3 avgpool, bf16 MFMA, 4096-block grid.
// R5: B-frags direct from global wT (L2), phased 9-at-a-time (36 VGPR).
// x-halo LDS layout [dihi][g][iw][o] (g=ci>>3,o=ci&7): staging = one
// ds_write_b128/thread/plane, 2-way banks (free); A-reads 2-way (free).
// Parity decomposition (validated R1-R4): even o: k=1,i=o/2;
//   odd o=2m+1: k=0 -> i=m+1 ; k=2 -> i=m.

typedef __attribute__((ext_vector_type(8))) short bf16x8;
typedef __attribute__((ext_vector_type(4))) float f32x4;

static __device__ __forceinline__ unsigned short f2bf(float f) {
    unsigned int u = __float_as_uint(f);
    u = (u + 0x7fffu + ((u >> 16) & 1u)) >> 16;   // RNE
    return (unsigned short)u;
}
static __device__ __forceinline__ unsigned pack2(float a, float b) {
    return (unsigned)f2bf(a) | ((unsigned)f2bf(b) << 16);
}

// ---- w convert: w[ci][co][tap] fp32 -> wT[tap][co][ci] bf16 (tap=kd*9+kh*3+kw)
__global__ __launch_bounds__(256)
void kw(const float* __restrict__ w, unsigned short* __restrict__ wT)
{
    const int idx = blockIdx.x * 256 + threadIdx.x;
    if (idx < 13824) {
        const int ci = idx & 31, co = (idx >> 5) & 15, tap = idx >> 9;
        wT[idx] = f2bf(w[(ci * 16 + co) * 27 + tap]);
    }
}

// ---- fused stage + convT + BN-stats + pool partials
__global__ __launch_bounds__(256, 3)
void convf2(const float* __restrict__ x,
            const unsigned short* __restrict__ wT,
            const float* __restrict__ bias,
            float* __restrict__ pooled,
            float* __restrict__ psum, float* __restrict__ psq)
{
    const int ht = blockIdx.x, dt = blockIdx.y, n = blockIdx.z;
    const int tid = threadIdx.x;
    const int v = tid >> 6, lane = tid & 63;
    const int t = v & 1, odp = v >> 1;          // ow 16-tile, od pair
    const int c = lane & 15, qd = lane >> 4;    // co / A-row m, K-granule

    // xs[dihi(9)][g(4)][iw(33)][o(8)] bf16 -> 9*1056 shorts = 19008 B
    __shared__ unsigned short xs[9504];
    __shared__ float sred[4][16], qred[4][16], pbuf[2][8][16];

    // ---- stage x: thread = (plane-half, g, iw); 8 ci-strided b32 loads,
    // pack -> one ds_write_b128. 5 passes cover 9 planes + zero column.
    #pragma unroll
    for (int p = 0; p < 5; ++p) {
        const int dihi = p * 2 + (tid >> 7);
        if (dihi < 9) {
            const int iw = tid & 31, g = (tid >> 5) & 3;
            const int di = dihi / 3, hi = dihi - di * 3;
            const int id = 2*dt + di, ih = 2*ht + hi;
            const bool ok = (id < 32) && (ih < 32);
            const float* px = x + ((((n*32 + g*8)*32 + id)*32 + ih)*32) + iw;
            float f[8];
            #pragma unroll
            for (int j = 0; j < 8; ++j)
                f[j] = ok ? px[j * 32768] : 0.f;
            uint4 u;
            u.x = pack2(f[0], f[1]); u.y = pack2(f[2], f[3]);
            u.z = pack2(f[4], f[5]); u.w = pack2(f[6], f[7]);
            *(uint4*)(xs + dihi*1056 + g*264 + iw*8) = u;
        }
    }
    if (tid < 36) {
        const int dihi = tid >> 2, g = tid & 3;
        *(uint4*)(xs + dihi*1056 + g*264 + 256) = make_uint4(0,0,0,0);
    }

    // ---- B phase 0 (kd=1) prefetched before the barrier (L2-resident wT)
    auto LDBg = [&](int tap) -> bf16x8 {
        return *(const bf16x8*)(wT + tap * 512 + c * 32 + qd * 8);
    };
    bf16x8 Ba[9];
    #pragma unroll
    for (int i = 0; i < 9; ++i) Ba[i] = LDBg(9 + i);

    __syncthreads();

    f32x4 acc[2][4][2];   // [ol][oh][par]
    #pragma unroll
    for (int ol = 0; ol < 2; ++ol)
        #pragma unroll
        for (int oh = 0; oh < 4; ++oh)
            #pragma unroll
            for (int par = 0; par < 2; ++par)
                acc[ol][oh][par] = (f32x4){0.f,0.f,0.f,0.f};

    const int iwb = 16 * t + c;
    auto LDA = [&](int dihi, int sofs) -> bf16x8 {
        return *(const bf16x8*)(xs + dihi*1056 + qd*264 + (iwb + sofs)*8);
    };

    // h-tap tables (validated R2-R4): hi -> (kh, ohl) pairs
    constexpr int HN[3] = {2, 3, 1};
    constexpr int HKH[3][3] = {{1,2,0},{0,1,2},{0,0,0}};
    constexpr int HOH[3][3] = {{0,1,0},{1,2,3},{3,0,0}};

    auto PH = [&](int ol, const bf16x8* B, int di) {
        #pragma unroll
        for (int hi = 0; hi < 3; ++hi) {
            const bf16x8 A0 = LDA(di*3 + hi, 0), A1 = LDA(di*3 + hi, 1);
            #pragma unroll
            for (int j = 0; j < 3; ++j)
                if (j < HN[hi]) {
                    const int kh = HKH[hi][j], oh = HOH[hi][j];
                    acc[ol][oh][0] = __builtin_amdgcn_mfma_f32_16x16x32_bf16(
                        A0, B[kh*3 + 1], acc[ol][oh][0], 0, 0, 0);
                    acc[ol][oh][1] = __builtin_amdgcn_mfma_f32_16x16x32_bf16(
                        A1, B[kh*3 + 0], acc[ol][oh][1], 0, 0, 0);
                    acc[ol][oh][1] = __builtin_amdgcn_mfma_f32_16x16x32_bf16(
                        A0, B[kh*3 + 2], acc[ol][oh][1], 0, 0, 0);
                }
        }
    };

    PH(0, Ba, odp);                                   // kd=1 -> ol0
    #pragma unroll
    for (int i = 0; i < 9; ++i) Ba[i] = LDBg(18 + i);
    PH(1, Ba, odp);                                   // kd=2 -> ol1
    #pragma unroll
    for (int i = 0; i < 9; ++i) Ba[i] = LDBg(i);
    PH(1, Ba, odp + 1);                               // kd=0 -> ol1

    // ---- epilogue: bias, BN stats (masked), pool partials (validated R2-R4)
    const float bv = bias[c];
    float s = 0.f, sq = 0.f;
    float P[2] = {0.f, 0.f};
    #pragma unroll
    for (int ol = 0; ol < 2; ++ol) {
        const int odg = 2*odp + ol;
        const bool odok = !(dt == 15 && odg == 3);
        #pragma unroll
        for (int oh = 0; oh < 4; ++oh) {
            const bool ohok = !(ht == 15 && oh == 3);
            #pragma unroll
            for (int par = 0; par < 2; ++par)
                #pragma unroll
                for (int r = 0; r < 4; ++r) {
                    const float val = acc[ol][oh][par][r] + bv;
                    const bool owok = !(par == 1 && t == 1 && qd == 3 && r == 3);
                    const float mk = (odok && ohok && owok) ? 1.f : 0.f;
                    s += mk * val; sq += mk * val * val;
                    P[r >> 1] += val;
                }
        }
    }
    s  += __shfl_xor(s, 16, 64);  s  += __shfl_xor(s, 32, 64);
    sq += __shfl_xor(sq, 16, 64); sq += __shfl_xor(sq, 32, 64);

    if (lane < 16) { sred[v][lane] = s; qred[v][lane] = sq; }
    if (odp == 0 && dt < 15 && ht < 15) {
        pbuf[t][2*qd + 0][c] = P[0];
        pbuf[t][2*qd + 1][c] = P[1];
    }
    __syncthreads();
    if (tid < 16) {
        const int blk = (n*16 + dt)*16 + ht;
        psum[tid*4096 + blk] = sred[0][tid]+sred[1][tid]+sred[2][tid]+sred[3][tid];
        psq [tid*4096 + blk] = qred[0][tid]+qred[1][tid]+qred[2][tid]+qred[3][tid];
    }
    if (odp == 1 && dt < 15 && ht < 15) {
        #pragma unroll
        for (int jj = 0; jj < 2; ++jj) {
            const int jl = 2*qd + jj, jg = 8*t + jl;
            if (jg < 15) {
                const float tot = pbuf[t][jl][c] + P[jj];
                pooled[(n*16 + c)*3375 + dt*225 + ht*15 + jg] = tot * (1.f/64.f);
            }
        }
    }
}

__global__ void bnfinal(const float* __restrict__ psum, const float* __restrict__ psq,
                        const float* __restrict__ gamma, const float* __restrict__ beta,
                        float* __restrict__ bn)
{
    const int co = blockIdx.x;
    const int t  = threadIdx.x;
    float S = 0, Q = 0;
    for (int blk = t; blk < 4096; blk += 256) {
        S += psum[co*4096 + blk];
        Q += psq [co*4096 + blk];
    }
    #pragma unroll
    for (int off = 32; off > 0; off >>= 1) {
        S += __shfl_down(S, off, 64);
        Q += __shfl_down(Q, off, 64);
    }
    __shared__ float rs[4], rq[4];
    if ((t & 63) == 0) { rs[t >> 6] = S; rq[t >> 6] = Q; }
    __syncthreads();
    if (t == 0) {
        S = rs[0] + rs[1] + rs[2] + rs[3];
        Q = rq[0] + rq[1] + rq[2] + rq[3];
        const float cnt = 16.f * 63.f * 63.f * 63.f;
        const float mean = S / cnt;
        const float var  = Q / cnt - mean * mean;
        const float inv  = rsqrtf(var + 1e-5f);
        const float sc   = inv * gamma[co];
        bn[co]      = sc;
        bn[16 + co] = beta[co] - mean * sc;
    }
}

__global__ void finalize(const float* __restrict__ pooled, const float* __restrict__ bn,
                         float* __restrict__ out)
{
    const int i  = blockIdx.x * 256 + threadIdx.x;   // 864000 = 3375*256
    const int co = (i / 3375) & 15;
    out[i] = pooled[i] * bn[co] + bn[16 + co];
}

extern "C" void kernel_launch(void* const* d_in, const int* in_sizes, int n_in,
                              void* d_out, int out_size, void* d_ws, size_t ws_size,
                              hipStream_t stream)
{
    const float* x     = (const float*)d_in[0];
    const float* w     = (const float*)d_in[1];
    const float* b     = (const float*)d_in[2];
    const float* gamma = (const float*)d_in[3];
    const float* beta  = (const float*)d_in[4];
    float* out = (float*)d_out;

    char* wsb = (char*)d_ws;
    unsigned short* wT = (unsigned short*)wsb;        // 27,648 B
    float* pooled = (float*)(wsb + 27648);            // 3,456,000 B
    float* psum   = (float*)(wsb + 27648 + 3456000);  // 262,144 B
    float* psq    = (float*)(wsb + 27648 + 3456000 + 262144);
    float* bn     = (float*)(wsb + 27648 + 3456000 + 2*262144);

    kw<<<54, 256, 0, stream>>>(w, wT);
    dim3 grid(16, 16, 16);   // (ht, dt, n)
    convf2<<<grid, 256, 0, stream>>>(x, wT, b, pooled, psum, psq);
    bnfinal<<<16, 256, 0, stream>>>(psum, psq, gamma, beta, bn);
    finalize<<<3375, 256, 0, stream>>>(pooled, bn, out);
}